// Round 6
// baseline (187.508 us; speedup 1.0000x reference)
//
#include <hip/hip_runtime.h>

#define B 8
#define TQ 64
#define TK 8192
#define H 256

#define KSPLIT 32
#define KPB (TK / KSPLIT)   // 256 k per context block

typedef __attribute__((ext_vector_type(8))) short bf16x8;
typedef __attribute__((ext_vector_type(4))) float f32x4;
typedef __attribute__((ext_vector_type(4))) unsigned short u16x4;
typedef __attribute__((ext_vector_type(2))) unsigned int u32x2;

static __device__ inline unsigned short f2bf_rne(float x) {
    unsigned int u = __float_as_uint(x);
    unsigned int r = (u + 0x7fffu + ((u >> 16) & 1u)) >> 16;   // RNE
    return (unsigned short)r;
}

// ---------------- Kernel 1: qt-split = (query @ Wa_w) hi/lo ; qb -----------
__global__ __launch_bounds__(256) void qtransform_kernel(
    const float* __restrict__ query, const float* __restrict__ Wa_w,
    const float* __restrict__ Wa_b, unsigned short* __restrict__ qthi,
    unsigned short* __restrict__ qtlo, float* __restrict__ qb)
{
    __shared__ float q_s[H];
    __shared__ float red[4];
    const int r = blockIdx.x;          // row in [0, B*TQ)
    const int t = threadIdx.x;         // 0..255
    q_s[t] = query[r * H + t];
    __syncthreads();

    float a0 = 0.f, a1 = 0.f, a2 = 0.f, a3 = 0.f;
    for (int o = 0; o < H; o += 4) {
        a0 += q_s[o + 0] * Wa_w[(o + 0) * H + t];
        a1 += q_s[o + 1] * Wa_w[(o + 1) * H + t];
        a2 += q_s[o + 2] * Wa_w[(o + 2) * H + t];
        a3 += q_s[o + 3] * Wa_w[(o + 3) * H + t];
    }
    const float s = (a0 + a1) + (a2 + a3);
    const unsigned int u = __float_as_uint(s);
    const float hif = __uint_as_float(u & 0xFFFF0000u);
    const float lof = s - hif;                     // exact
    qthi[r * H + t] = (unsigned short)(u >> 16);
    qtlo[r * H + t] = (unsigned short)(__float_as_uint(lof) >> 16);

    float p = q_s[t] * Wa_b[t];
    for (int off = 32; off > 0; off >>= 1) p += __shfl_down(p, off, 64);
    if ((t & 63) == 0) red[t >> 6] = p;
    __syncthreads();
    if (t == 0) qb[r] = (red[0] + red[1]) + (red[2] + red[3]);
}

// ---------------- Kernel 2: scores (bf16-split MFMA, dbuf, 1 barrier/iter) -
// grid (TK/64=128, B); block 256 (4 waves). Tile 64q x 64k, K = H = 256.
// A-frags direct from global qt-split (L2-hot). Keys tile -> swizzled LDS.
// Also writes khiT [B][H][TK] (transposed bf16-hi keys) for context.

// convert one float4 (k-row `row`, h-cols hf*4..+3) -> swizzled LDS + khiT
#define STAGE1(v, row, buf, khb) {                                             \
    unsigned int u0=__float_as_uint(v.x), u1=__float_as_uint(v.y);             \
    unsigned int u2=__float_as_uint(v.z), u3=__float_as_uint(v.w);             \
    unsigned int h01=(u0>>16)|(u1&0xFFFF0000u), h23=(u2>>16)|(u3&0xFFFF0000u); \
    float l0=v.x-__uint_as_float(u0&0xFFFF0000u);                              \
    float l1=v.y-__uint_as_float(u1&0xFFFF0000u);                              \
    float l2=v.z-__uint_as_float(u2&0xFFFF0000u);                              \
    float l3=v.w-__uint_as_float(u3&0xFFFF0000u);                              \
    unsigned int q01=(__float_as_uint(l0)>>16)|(__float_as_uint(l1)&0xFFFF0000u); \
    unsigned int q23=(__float_as_uint(l2)>>16)|(__float_as_uint(l3)&0xFFFF0000u); \
    int bo=(row)*128 + (((hf>>1)^((row)&7))<<4) + ((hf&1)<<3);                 \
    *(u32x2*)((char*)b_hi[buf]+bo) = (u32x2){h01,h23};                         \
    *(u32x2*)((char*)b_lo[buf]+bo) = (u32x2){q01,q23};                         \
    khb[(size_t)(hf*4+0)*TK + (row)] = (unsigned short)(u0>>16);               \
    khb[(size_t)(hf*4+1)*TK + (row)] = (unsigned short)(u1>>16);               \
    khb[(size_t)(hf*4+2)*TK + (row)] = (unsigned short)(u2>>16);               \
    khb[(size_t)(hf*4+3)*TK + (row)] = (unsigned short)(u3>>16); }

#define LOADCHUNK(d0,d1,d2,d3, hc)                                             \
    d0 = *(const float4*)&kbase_g[(size_t)(sr +  0) * H + (hc) + hf * 4];      \
    d1 = *(const float4*)&kbase_g[(size_t)(sr + 16) * H + (hc) + hf * 4];      \
    d2 = *(const float4*)&kbase_g[(size_t)(sr + 32) * H + (hc) + hf * 4];      \
    d3 = *(const float4*)&kbase_g[(size_t)(sr + 48) * H + (hc) + hf * 4];

#define STAGECHUNK(v0,v1,v2,v3, buf, hc) {                                     \
    unsigned short* khb = khiT + ((size_t)b * H + (hc)) * TK + k0g;            \
    STAGE1(v0, sr +  0, buf, khb); STAGE1(v1, sr + 16, buf, khb);              \
    STAGE1(v2, sr + 32, buf, khb); STAGE1(v3, sr + 48, buf, khb); }

#define COMPUTE(buf, hc) {                                                     \
    _Pragma("unroll")                                                          \
    for (int hs = 0; hs < 64; hs += 32) {                                      \
        bf16x8 ah = *(const bf16x8*)&ah_base[(hc) + hs + lgrp * 8];            \
        bf16x8 al = *(const bf16x8*)&al_base[(hc) + hs + lgrp * 8];            \
        _Pragma("unroll")                                                      \
        for (int nt = 0; nt < 4; ++nt) {                                       \
            int rr = 16 * nt + lrow;                                           \
            int rb = rr * 128 + ((((hs >> 3) + lgrp) ^ (rr & 7)) << 4);        \
            bf16x8 bh = *(const bf16x8*)((const char*)b_hi[buf] + rb);         \
            bf16x8 bl = *(const bf16x8*)((const char*)b_lo[buf] + rb);         \
            acc[nt] = __builtin_amdgcn_mfma_f32_16x16x32_bf16(ah, bh, acc[nt], 0, 0, 0); \
            acc[nt] = __builtin_amdgcn_mfma_f32_16x16x32_bf16(ah, bl, acc[nt], 0, 0, 0); \
            acc[nt] = __builtin_amdgcn_mfma_f32_16x16x32_bf16(al, bh, acc[nt], 0, 0, 0); \
        } } }

__global__ __launch_bounds__(256, 4) void scores_kernel(
    const unsigned short* __restrict__ qthi, const unsigned short* __restrict__ qtlo,
    const float* __restrict__ qb, const float* __restrict__ keys,
    unsigned short* __restrict__ khiT, float* __restrict__ wout)
{
    __shared__ unsigned short b_hi[2][64 * 64];   // swizzled, stride 64
    __shared__ unsigned short b_lo[2][64 * 64];
    const int t    = threadIdx.x;
    const int kt   = blockIdx.x;     // 0..127
    const int b    = blockIdx.y;     // 0..7
    const int k0g  = kt * 64;
    const int w    = t >> 6;         // wave -> q rows 16w..16w+15
    const int lane = t & 63;
    const int lrow = lane & 15;
    const int lgrp = lane >> 4;      // 0..3
    const int sr   = t >> 4;         // staging base k-row 0..15
    const int hf   = t & 15;         // staging h-group

    const float* kbase_g = keys + (size_t)(b * TK + k0g) * H;
    const unsigned short* ah_base = qthi + (size_t)(b * TQ + 16 * w + lrow) * H;
    const unsigned short* al_base = qtlo + (size_t)(b * TQ + 16 * w + lrow) * H;

    f32x4 acc[4];
    #pragma unroll
    for (int nt = 0; nt < 4; ++nt) acc[nt] = (f32x4){0.f, 0.f, 0.f, 0.f};

    float4 a0, a1, a2, a3, c0, c1, c2, c3;
    LOADCHUNK(a0, a1, a2, a3, 0)

    LOADCHUNK(c0, c1, c2, c3, 64)          // prefetch chunk 1
    STAGECHUNK(a0, a1, a2, a3, 0, 0)
    __syncthreads();
    COMPUTE(0, 0)

    LOADCHUNK(a0, a1, a2, a3, 128)         // prefetch chunk 2
    STAGECHUNK(c0, c1, c2, c3, 1, 64)
    __syncthreads();
    COMPUTE(1, 64)

    LOADCHUNK(c0, c1, c2, c3, 192)         // prefetch chunk 3
    STAGECHUNK(a0, a1, a2, a3, 0, 128)
    __syncthreads();
    COMPUTE(0, 128)

    STAGECHUNK(c0, c1, c2, c3, 1, 192)
    __syncthreads();
    COMPUTE(1, 192)

    // epilogue: D col = lane&15 (k), row = lgrp*4 + j (q)
    #pragma unroll
    for (int j = 0; j < 4; ++j) {
        const int qrow = 16 * w + lgrp * 4 + j;
        const float bias = qb[b * TQ + qrow];
        float* dst = &wout[(size_t)(b * TQ + qrow) * TK + k0g + lrow];
        #pragma unroll
        for (int nt = 0; nt < 4; ++nt) dst[16 * nt] = acc[nt][j] + bias;
    }
}

// ---------------- Kernel 3: row softmax in place + phi (bf16) side-output --
__global__ __launch_bounds__(1024) void softmax_kernel(
    float* __restrict__ w, unsigned short* __restrict__ phi)
{
    const int r = blockIdx.x;     // 0..511
    const int t = threadIdx.x;    // 0..1023
    float4* row4 = (float4*)(w + (size_t)r * TK);
    __shared__ float redm[16];
    __shared__ float reds[16];
    const int wid = t >> 6, lane = t & 63;

    float4 v0 = row4[t];
    float4 v1 = row4[t + 1024];
    float m = fmaxf(fmaxf(fmaxf(v0.x, v0.y), fmaxf(v0.z, v0.w)),
                    fmaxf(fmaxf(v1.x, v1.y), fmaxf(v1.z, v1.w)));
    for (int off = 32; off > 0; off >>= 1) m = fmaxf(m, __shfl_xor(m, off, 64));
    if (lane == 0) redm[wid] = m;
    __syncthreads();
    m = redm[0];
    #pragma unroll
    for (int i = 1; i < 16; ++i) m = fmaxf(m, redm[i]);

    v0.x = __expf(v0.x - m); v0.y = __expf(v0.y - m);
    v0.z = __expf(v0.z - m); v0.w = __expf(v0.w - m);
    v1.x = __expf(v1.x - m); v1.y = __expf(v1.y - m);
    v1.z = __expf(v1.z - m); v1.w = __expf(v1.w - m);
    float s = (v0.x + v0.y + v0.z + v0.w) + (v1.x + v1.y + v1.z + v1.w);
    for (int off = 32; off > 0; off >>= 1) s += __shfl_xor(s, off, 64);
    if (lane == 0) reds[wid] = s;
    __syncthreads();
    s = reds[0];
    #pragma unroll
    for (int i = 1; i < 16; ++i) s += reds[i];
    const float inv = 1.0f / s;

    v0.x *= inv; v0.y *= inv; v0.z *= inv; v0.w *= inv;
    v1.x *= inv; v1.y *= inv; v1.z *= inv; v1.w *= inv;
    row4[t] = v0;
    row4[t + 1024] = v1;

    unsigned short* prow = phi + (size_t)r * TK;
    u16x4 p0, p1;
    p0[0] = f2bf_rne(v0.x); p0[1] = f2bf_rne(v0.y);
    p0[2] = f2bf_rne(v0.z); p0[3] = f2bf_rne(v0.w);
    p1[0] = f2bf_rne(v1.x); p1[1] = f2bf_rne(v1.y);
    p1[2] = f2bf_rne(v1.z); p1[3] = f2bf_rne(v1.w);
    *(u16x4*)&prow[t * 4] = p0;
    *(u16x4*)&prow[4096 + t * 4] = p1;
}

// ---------------- Kernel 4a: context partials via MFMA -- NO LDS, NO BARRIER
// grid (KSPLIT, 4, B); block 256 (4 waves). 64q x 64h tile over KPB=256 k.
// A-frag: phi [q][k-contig]. B-frag: khiT [h][k-contig]. All direct global.
__global__ __launch_bounds__(256) void context_main_kernel(
    const unsigned short* __restrict__ phi, const unsigned short* __restrict__ khiT,
    float* __restrict__ part)
{
    const int t    = threadIdx.x;
    const int ks   = blockIdx.x;     // 0..KSPLIT-1
    const int ht   = blockIdx.y;     // 0..3
    const int b    = blockIdx.z;     // 0..7
    const int w    = t >> 6;
    const int lane = t & 63;
    const int lrow = lane & 15;
    const int lgrp = lane >> 4;
    const int kbase = ks * KPB;

    const unsigned short* arow = phi + (size_t)(b * TQ + 16 * w + lrow) * TK
                                     + kbase + lgrp * 8;
    const unsigned short* brow = khiT + (size_t)(b * H + ht * 64 + lrow) * TK
                                      + kbase + lgrp * 8;

    f32x4 acc[4];
    #pragma unroll
    for (int nt = 0; nt < 4; ++nt) acc[nt] = (f32x4){0.f, 0.f, 0.f, 0.f};

    #pragma unroll 2
    for (int c = 0; c < KPB; c += 32) {
        bf16x8 af = *(const bf16x8*)&arow[c];
        #pragma unroll
        for (int nt = 0; nt < 4; ++nt) {
            bf16x8 bfg = *(const bf16x8*)&brow[(size_t)(16 * nt) * TK + c];
            acc[nt] = __builtin_amdgcn_mfma_f32_16x16x32_bf16(af, bfg, acc[nt], 0, 0, 0);
        }
    }
    float* dst = part + (size_t)ks * (B * TQ * H);
    #pragma unroll
    for (int j = 0; j < 4; ++j) {
        const int qrow = 16 * w + lgrp * 4 + j;
        #pragma unroll
        for (int nt = 0; nt < 4; ++nt)
            dst[(size_t)(b * TQ + qrow) * H + ht * 64 + 16 * nt + lrow] = acc[nt][j];
    }
}

// ---------------- Kernel 4b: reduce partials -> ctx ------------------------
__global__ __launch_bounds__(256) void context_reduce_kernel(
    const float* __restrict__ part, float* __restrict__ ctx)
{
    const int idx = blockIdx.x * 256 + threadIdx.x;   // float4 index, 32768 total
    float4 s = make_float4(0.f, 0.f, 0.f, 0.f);
    #pragma unroll 8
    for (int ks = 0; ks < KSPLIT; ++ks) {
        float4 v = *(const float4*)&part[(size_t)ks * (B * TQ * H) + (size_t)idx * 4];
        s.x += v.x; s.y += v.y; s.z += v.z; s.w += v.w;
    }
    *(float4*)&ctx[(size_t)idx * 4] = s;
}

extern "C" void kernel_launch(void* const* d_in, const int* in_sizes, int n_in,
                              void* d_out, int out_size, void* d_ws, size_t ws_size,
                              hipStream_t stream) {
    const float* query = (const float*)d_in[0];
    const float* keys  = (const float*)d_in[1];
    const float* Wa_w  = (const float*)d_in[2];
    const float* Wa_b  = (const float*)d_in[3];

    float* ctx = (float*)d_out;                 // [B,TQ,H]
    float* wts = (float*)d_out + B * TQ * H;    // [B,TQ,TK]

    char* p = (char*)d_ws;
    float* part = (float*)p;                    p += (size_t)KSPLIT * B * TQ * H * 4;
    unsigned short* khiT = (unsigned short*)p;  p += (size_t)B * H * TK * 2;
    unsigned short* phi = (unsigned short*)p;   p += (size_t)B * TQ * TK * 2;
    unsigned short* qthi = (unsigned short*)p;  p += (size_t)B * TQ * H * 2;
    unsigned short* qtlo = (unsigned short*)p;  p += (size_t)B * TQ * H * 2;
    float* qb = (float*)p;

    qtransform_kernel<<<B * TQ, 256, 0, stream>>>(query, Wa_w, Wa_b, qthi, qtlo, qb);
    scores_kernel<<<dim3(TK / 64, B), 256, 0, stream>>>(qthi, qtlo, qb, keys, khiT, wts);
    softmax_kernel<<<B * TQ, 1024, 0, stream>>>(wts, phi);
    context_main_kernel<<<dim3(KSPLIT, 4, B), 256, 0, stream>>>(phi, khiT, part);
    context_reduce_kernel<<<(B * TQ * H / 4) / 256, 256, 0, stream>>>(part, ctx);
}

// Round 7
// 146.590 us; speedup vs baseline: 1.2791x; 1.2791x over previous
//
#include <hip/hip_runtime.h>

#define B 8
#define TQ 64
#define TK 8192
#define H 256

#define KSPLIT 32
#define KPB (TK / KSPLIT)   // 256 k per context block
#define CRS 72              // context LDS keysT row stride (ushorts)

typedef __attribute__((ext_vector_type(8))) short bf16x8;
typedef __attribute__((ext_vector_type(4))) float f32x4;
typedef __attribute__((ext_vector_type(4))) unsigned short u16x4;
typedef __attribute__((ext_vector_type(2))) unsigned int u32x2;

static __device__ inline unsigned short f2bf_rne(float x) {
    unsigned int u = __float_as_uint(x);
    unsigned int r = (u + 0x7fffu + ((u >> 16) & 1u)) >> 16;   // RNE
    return (unsigned short)r;
}

// ---------------- Kernel 1: qt-split = (query @ Wa_w) hi/lo ; qb -----------
__global__ __launch_bounds__(256) void qtransform_kernel(
    const float* __restrict__ query, const float* __restrict__ Wa_w,
    const float* __restrict__ Wa_b, unsigned short* __restrict__ qthi,
    unsigned short* __restrict__ qtlo, float* __restrict__ qb)
{
    __shared__ float q_s[H];
    __shared__ float red[4];
    const int r = blockIdx.x;          // row in [0, B*TQ)
    const int t = threadIdx.x;         // 0..255
    q_s[t] = query[r * H + t];
    __syncthreads();

    float a0 = 0.f, a1 = 0.f, a2 = 0.f, a3 = 0.f;
    for (int o = 0; o < H; o += 4) {
        a0 += q_s[o + 0] * Wa_w[(o + 0) * H + t];
        a1 += q_s[o + 1] * Wa_w[(o + 1) * H + t];
        a2 += q_s[o + 2] * Wa_w[(o + 2) * H + t];
        a3 += q_s[o + 3] * Wa_w[(o + 3) * H + t];
    }
    const float s = (a0 + a1) + (a2 + a3);
    const unsigned int u = __float_as_uint(s);
    const float hif = __uint_as_float(u & 0xFFFF0000u);
    const float lof = s - hif;                     // exact
    qthi[r * H + t] = (unsigned short)(u >> 16);
    qtlo[r * H + t] = (unsigned short)(__float_as_uint(lof) >> 16);

    float p = q_s[t] * Wa_b[t];
    for (int off = 32; off > 0; off >>= 1) p += __shfl_down(p, off, 64);
    if ((t & 63) == 0) red[t >> 6] = p;
    __syncthreads();
    if (t == 0) qb[r] = (red[0] + red[1]) + (red[2] + red[3]);
}

// ---------------- Kernel 2: scores (bf16-split MFMA, prefetch, 32KB LDS) ---
// grid (TK/64=128, B); block 256 (4 waves). Tile 64q x 64k, K = H = 256.
// A-frags direct from global qt-split (L2-hot). Keys tile -> swizzled LDS
// (single buffer). khi side-write in coalesced [b][k][h] bf16 layout.

#define STAGE1(v, row, khb) {                                                  \
    unsigned int u0=__float_as_uint(v.x), u1=__float_as_uint(v.y);             \
    unsigned int u2=__float_as_uint(v.z), u3=__float_as_uint(v.w);             \
    unsigned int h01=(u0>>16)|(u1&0xFFFF0000u), h23=(u2>>16)|(u3&0xFFFF0000u); \
    float l0=v.x-__uint_as_float(u0&0xFFFF0000u);                              \
    float l1=v.y-__uint_as_float(u1&0xFFFF0000u);                              \
    float l2=v.z-__uint_as_float(u2&0xFFFF0000u);                              \
    float l3=v.w-__uint_as_float(u3&0xFFFF0000u);                              \
    unsigned int q01=(__float_as_uint(l0)>>16)|(__float_as_uint(l1)&0xFFFF0000u); \
    unsigned int q23=(__float_as_uint(l2)>>16)|(__float_as_uint(l3)&0xFFFF0000u); \
    int bo=(row)*128 + (((hf>>1)^((row)&7))<<4) + ((hf&1)<<3);                 \
    *(u32x2*)((char*)b_hi+bo) = (u32x2){h01,h23};                              \
    *(u32x2*)((char*)b_lo+bo) = (u32x2){q01,q23};                              \
    *(u32x2*)&khb[(size_t)(row)*H + hf*4] = (u32x2){h01,h23}; }

#define LOADCHUNK(d0,d1,d2,d3, hc)                                             \
    d0 = *(const float4*)&kbase_g[(size_t)(sr +  0) * H + (hc) + hf * 4];      \
    d1 = *(const float4*)&kbase_g[(size_t)(sr + 16) * H + (hc) + hf * 4];      \
    d2 = *(const float4*)&kbase_g[(size_t)(sr + 32) * H + (hc) + hf * 4];      \
    d3 = *(const float4*)&kbase_g[(size_t)(sr + 48) * H + (hc) + hf * 4];

#define STAGECHUNK(v0,v1,v2,v3, hc) {                                          \
    unsigned short* khb = khi_ws + ((size_t)b * TK + k0g) * H + (hc);          \
    STAGE1(v0, sr +  0, khb); STAGE1(v1, sr + 16, khb);                        \
    STAGE1(v2, sr + 32, khb); STAGE1(v3, sr + 48, khb); }

#define COMPUTE(hc) {                                                          \
    _Pragma("unroll")                                                          \
    for (int hs = 0; hs < 64; hs += 32) {                                      \
        bf16x8 ah = *(const bf16x8*)&ah_base[(hc) + hs + lgrp * 8];            \
        bf16x8 al = *(const bf16x8*)&al_base[(hc) + hs + lgrp * 8];            \
        _Pragma("unroll")                                                      \
        for (int nt = 0; nt < 4; ++nt) {                                       \
            int rr = 16 * nt + lrow;                                           \
            int rb = rr * 128 + ((((hs >> 3) + lgrp) ^ (rr & 7)) << 4);        \
            bf16x8 bh = *(const bf16x8*)((const char*)b_hi + rb);              \
            bf16x8 bl = *(const bf16x8*)((const char*)b_lo + rb);              \
            acc[nt] = __builtin_amdgcn_mfma_f32_16x16x32_bf16(ah, bh, acc[nt], 0, 0, 0); \
            acc[nt] = __builtin_amdgcn_mfma_f32_16x16x32_bf16(ah, bl, acc[nt], 0, 0, 0); \
            acc[nt] = __builtin_amdgcn_mfma_f32_16x16x32_bf16(al, bh, acc[nt], 0, 0, 0); \
        } } }

__global__ __launch_bounds__(256, 4) void scores_kernel(
    const unsigned short* __restrict__ qthi, const unsigned short* __restrict__ qtlo,
    const float* __restrict__ qb, const float* __restrict__ keys,
    unsigned short* __restrict__ khi_ws, float* __restrict__ wout)
{
    __shared__ unsigned short b_hi[64 * 64];   // swizzled, row stride 128B
    __shared__ unsigned short b_lo[64 * 64];
    const int t    = threadIdx.x;
    const int kt   = blockIdx.x;     // 0..127
    const int b    = blockIdx.y;     // 0..7
    const int k0g  = kt * 64;
    const int w    = t >> 6;         // wave -> q rows 16w..16w+15
    const int lane = t & 63;
    const int lrow = lane & 15;
    const int lgrp = lane >> 4;      // 0..3
    const int sr   = t >> 4;         // staging base k-row 0..15
    const int hf   = t & 15;         // staging h-group

    const float* kbase_g = keys + (size_t)(b * TK + k0g) * H;
    const unsigned short* ah_base = qthi + (size_t)(b * TQ + 16 * w + lrow) * H;
    const unsigned short* al_base = qtlo + (size_t)(b * TQ + 16 * w + lrow) * H;

    f32x4 acc[4];
    #pragma unroll
    for (int nt = 0; nt < 4; ++nt) acc[nt] = (f32x4){0.f, 0.f, 0.f, 0.f};

    float4 r0, r1, r2, r3, p0, p1, p2, p3;
    LOADCHUNK(r0, r1, r2, r3, 0)

    LOADCHUNK(p0, p1, p2, p3, 64)        // prefetch chunk 1 (in flight all iter0)
    STAGECHUNK(r0, r1, r2, r3, 0)
    __syncthreads();
    COMPUTE(0)
    __syncthreads();

    LOADCHUNK(r0, r1, r2, r3, 128)       // prefetch chunk 2
    STAGECHUNK(p0, p1, p2, p3, 64)
    __syncthreads();
    COMPUTE(64)
    __syncthreads();

    LOADCHUNK(p0, p1, p2, p3, 192)       // prefetch chunk 3
    STAGECHUNK(r0, r1, r2, r3, 128)
    __syncthreads();
    COMPUTE(128)
    __syncthreads();

    STAGECHUNK(p0, p1, p2, p3, 192)
    __syncthreads();
    COMPUTE(192)

    // epilogue: D col = lane&15 (k), row = lgrp*4 + j (q)
    #pragma unroll
    for (int j = 0; j < 4; ++j) {
        const int qrow = 16 * w + lgrp * 4 + j;
        const float bias = qb[b * TQ + qrow];
        float* dst = &wout[(size_t)(b * TQ + qrow) * TK + k0g + lrow];
        #pragma unroll
        for (int nt = 0; nt < 4; ++nt) dst[16 * nt] = acc[nt][j] + bias;
    }
}

// ---------------- Kernel 3: row softmax in place + phi (bf16) side-output --
__global__ __launch_bounds__(1024) void softmax_kernel(
    float* __restrict__ w, unsigned short* __restrict__ phi)
{
    const int r = blockIdx.x;     // 0..511
    const int t = threadIdx.x;    // 0..1023
    float4* row4 = (float4*)(w + (size_t)r * TK);
    __shared__ float redm[16];
    __shared__ float reds[16];
    const int wid = t >> 6, lane = t & 63;

    float4 v0 = row4[t];
    float4 v1 = row4[t + 1024];
    float m = fmaxf(fmaxf(fmaxf(v0.x, v0.y), fmaxf(v0.z, v0.w)),
                    fmaxf(fmaxf(v1.x, v1.y), fmaxf(v1.z, v1.w)));
    for (int off = 32; off > 0; off >>= 1) m = fmaxf(m, __shfl_xor(m, off, 64));
    if (lane == 0) redm[wid] = m;
    __syncthreads();
    m = redm[0];
    #pragma unroll
    for (int i = 1; i < 16; ++i) m = fmaxf(m, redm[i]);

    v0.x = __expf(v0.x - m); v0.y = __expf(v0.y - m);
    v0.z = __expf(v0.z - m); v0.w = __expf(v0.w - m);
    v1.x = __expf(v1.x - m); v1.y = __expf(v1.y - m);
    v1.z = __expf(v1.z - m); v1.w = __expf(v1.w - m);
    float s = (v0.x + v0.y + v0.z + v0.w) + (v1.x + v1.y + v1.z + v1.w);
    for (int off = 32; off > 0; off >>= 1) s += __shfl_xor(s, off, 64);
    if (lane == 0) reds[wid] = s;
    __syncthreads();
    s = reds[0];
    #pragma unroll
    for (int i = 1; i < 16; ++i) s += reds[i];
    const float inv = 1.0f / s;

    v0.x *= inv; v0.y *= inv; v0.z *= inv; v0.w *= inv;
    v1.x *= inv; v1.y *= inv; v1.z *= inv; v1.w *= inv;
    row4[t] = v0;
    row4[t + 1024] = v1;

    unsigned short* prow = phi + (size_t)r * TK;
    u16x4 pk0, pk1;
    pk0[0] = f2bf_rne(v0.x); pk0[1] = f2bf_rne(v0.y);
    pk0[2] = f2bf_rne(v0.z); pk0[3] = f2bf_rne(v0.w);
    pk1[0] = f2bf_rne(v1.x); pk1[1] = f2bf_rne(v1.y);
    pk1[2] = f2bf_rne(v1.z); pk1[3] = f2bf_rne(v1.w);
    *(u16x4*)&prow[t * 4] = pk0;
    *(u16x4*)&prow[4096 + t * 4] = pk1;
}

// ---------------- Kernel 4a: context partials via MFMA (split-k) -----------
// grid (KSPLIT, 4, B); block 256 (4 waves). 64q x 64h tile over KPB=256 k.
// B-operand keys^T built in LDS from coalesced khi via k-block XOR swizzle.
__global__ __launch_bounds__(256) void context_main_kernel(
    const unsigned short* __restrict__ phi, const unsigned short* __restrict__ khi,
    float* __restrict__ part)
{
    __shared__ unsigned short kT[64 * CRS];   // [h][k] transposed, swizzled
    const int t    = threadIdx.x;
    const int ks   = blockIdx.x;     // 0..KSPLIT-1
    const int ht   = blockIdx.y;     // 0..3
    const int b    = blockIdx.z;     // 0..7
    const int w    = t >> 6;         // wave -> q rows 16w..16w+15
    const int lane = t & 63;
    const int lrow = lane & 15;
    const int lgrp = lane >> 4;

    f32x4 acc[4];
    #pragma unroll
    for (int nt = 0; nt < 4; ++nt) acc[nt] = (f32x4){0.f, 0.f, 0.f, 0.f};

    const int kbase = ks * KPB;
    for (int c = 0; c < KPB; c += 64) {
        __syncthreads();
        // stage khi tile [64k][64h] -> kT[h][k] with kblk ^= (h>>3)&7 swizzle
        #pragma unroll
        for (int i = 0; i < 4; ++i) {
            int idx = t + 256 * i;
            int k = idx >> 4, hq = idx & 15;
            u16x4 v = *(const u16x4*)&khi[((size_t)b * TK + kbase + c + k) * H + ht * 64 + hq * 4];
            #pragma unroll
            for (int c4 = 0; c4 < 4; ++c4) {
                int h = hq * 4 + c4;
                kT[h * CRS + (((k >> 3) ^ ((h >> 3) & 7)) << 3) + (k & 7)] = v[c4];
            }
        }
        __syncthreads();
        #pragma unroll
        for (int kc = 0; kc < 64; kc += 32) {
            bf16x8 af = *(const bf16x8*)&phi[((size_t)(b * TQ) + 16 * w + lrow) * TK
                                             + kbase + c + kc + lgrp * 8];
            #pragma unroll
            for (int nt = 0; nt < 4; ++nt) {
                int h = 16 * nt + lrow;
                bf16x8 bfg = *(const bf16x8*)&kT[h * CRS
                              + ((((kc >> 3) + lgrp) ^ ((h >> 3) & 7)) << 3)];
                acc[nt] = __builtin_amdgcn_mfma_f32_16x16x32_bf16(af, bfg, acc[nt], 0, 0, 0);
            }
        }
    }
    // D: col = lane&15 (h), row = lgrp*4 + j (q)
    float* dst = part + (size_t)ks * (B * TQ * H);
    #pragma unroll
    for (int j = 0; j < 4; ++j) {
        const int qrow = 16 * w + lgrp * 4 + j;
        #pragma unroll
        for (int nt = 0; nt < 4; ++nt)
            dst[(size_t)(b * TQ + qrow) * H + ht * 64 + 16 * nt + lrow] = acc[nt][j];
    }
}

// ---------------- Kernel 4b: reduce partials -> ctx ------------------------
__global__ __launch_bounds__(256) void context_reduce_kernel(
    const float* __restrict__ part, float* __restrict__ ctx)
{
    const int idx = blockIdx.x * 256 + threadIdx.x;   // float4 index, 32768 total
    float4 s = make_float4(0.f, 0.f, 0.f, 0.f);
    #pragma unroll 8
    for (int ks = 0; ks < KSPLIT; ++ks) {
        float4 v = *(const float4*)&part[(size_t)ks * (B * TQ * H) + (size_t)idx * 4];
        s.x += v.x; s.y += v.y; s.z += v.z; s.w += v.w;
    }
    *(float4*)&ctx[(size_t)idx * 4] = s;
}

extern "C" void kernel_launch(void* const* d_in, const int* in_sizes, int n_in,
                              void* d_out, int out_size, void* d_ws, size_t ws_size,
                              hipStream_t stream) {
    const float* query = (const float*)d_in[0];
    const float* keys  = (const float*)d_in[1];
    const float* Wa_w  = (const float*)d_in[2];
    const float* Wa_b  = (const float*)d_in[3];

    float* ctx = (float*)d_out;                 // [B,TQ,H]
    float* wts = (float*)d_out + B * TQ * H;    // [B,TQ,TK]

    char* p = (char*)d_ws;
    float* part = (float*)p;                    p += (size_t)KSPLIT * B * TQ * H * 4;
    unsigned short* khi = (unsigned short*)p;   p += (size_t)B * TK * H * 2;
    unsigned short* phi = (unsigned short*)p;   p += (size_t)B * TQ * TK * 2;
    unsigned short* qthi = (unsigned short*)p;  p += (size_t)B * TQ * H * 2;
    unsigned short* qtlo = (unsigned short*)p;  p += (size_t)B * TQ * H * 2;
    float* qb = (float*)p;

    qtransform_kernel<<<B * TQ, 256, 0, stream>>>(query, Wa_w, Wa_b, qthi, qtlo, qb);
    scores_kernel<<<dim3(TK / 64, B), 256, 0, stream>>>(qthi, qtlo, qb, keys, khi, wts);
    softmax_kernel<<<B * TQ, 1024, 0, stream>>>(wts, phi);
    context_main_kernel<<<dim3(KSPLIT, 4, B), 256, 0, stream>>>(phi, khi, part);
    context_reduce_kernel<<<(B * TQ * H / 4) / 256, 256, 0, stream>>>(part, ctx);
}